// Round 1
// baseline (765.154 us; speedup 1.0000x reference)
//
#include <hip/hip_runtime.h>
#include <math.h>

#define BB 8
#define VV 32000
#define SS 512
#define NCHUNK 64
#define CHUNK (VV / NCHUNK)     // 500
#define NCOL (BB * SS)          // 4096
#define NGRAM 4
#define PP (SS - NGRAM)         // 508

// Kernel A: per-column (b,s) partial stats over a V-chunk.
// Each block: one b, one chunk of 500 v-rows. 256 threads:
//   vo = tid>>7 (which of 2 interleaved v streams), s = (tid&127)*4 (4 columns/thread, float4 loads).
__global__ __launch_bounds__(256) void colstats_kernel(const float* __restrict__ pred,
                                                       float* __restrict__ pmax,
                                                       float* __restrict__ psum,
                                                       int* __restrict__ pidx) {
    const int bid = blockIdx.x;
    const int b   = bid >> 6;            // / NCHUNK
    const int c   = bid & (NCHUNK - 1);
    const int tid = threadIdx.x;
    const int vo  = tid >> 7;
    const int s   = (tid & 127) << 2;
    const int v0  = c * CHUNK;

    float m0 = -INFINITY, m1 = -INFINITY, m2 = -INFINITY, m3 = -INFINITY;
    float a0 = 0.f, a1 = 0.f, a2 = 0.f, a3 = 0.f;
    int   i0 = 0, i1 = 0, i2 = 0, i3 = 0;

    const float L2E = 1.4426950408889634f;
    const float* ptr = pred + ((size_t)(b * VV + v0 + vo)) * SS + s;
#pragma unroll 4
    for (int v = v0 + vo; v < v0 + CHUNK; v += 2) {
        const float4 x = *(const float4*)ptr;
        ptr += 2 * SS;
        a0 += exp2f(x.x * L2E);
        a1 += exp2f(x.y * L2E);
        a2 += exp2f(x.z * L2E);
        a3 += exp2f(x.w * L2E);
        if (x.x > m0) { m0 = x.x; i0 = v; }
        if (x.y > m1) { m1 = x.y; i1 = v; }
        if (x.z > m2) { m2 = x.z; i2 = v; }
        if (x.w > m3) { m3 = x.w; i3 = v; }
    }

    __shared__ float smax[256][4];
    __shared__ float ssum[256][4];
    __shared__ int   sidx[256][4];
    smax[tid][0] = m0; smax[tid][1] = m1; smax[tid][2] = m2; smax[tid][3] = m3;
    ssum[tid][0] = a0; ssum[tid][1] = a1; ssum[tid][2] = a2; ssum[tid][3] = a3;
    sidx[tid][0] = i0; sidx[tid][1] = i1; sidx[tid][2] = i2; sidx[tid][3] = i3;
    __syncthreads();

    if (tid < 128) {
        const int o = tid + 128;
        float m[4]  = {smax[tid][0], smax[tid][1], smax[tid][2], smax[tid][3]};
        float a[4]  = {ssum[tid][0], ssum[tid][1], ssum[tid][2], ssum[tid][3]};
        int   ix[4] = {sidx[tid][0], sidx[tid][1], sidx[tid][2], sidx[tid][3]};
#pragma unroll
        for (int j = 0; j < 4; ++j) {
            const float om = smax[o][j];
            const int   oi = sidx[o][j];
            a[j] += ssum[o][j];
            if (om > m[j] || (om == m[j] && oi < ix[j])) { m[j] = om; ix[j] = oi; }
        }
        const size_t ob = (size_t)c * NCOL + (size_t)b * SS + (size_t)s;
#pragma unroll
        for (int j = 0; j < 4; ++j) {
            pmax[ob + j] = m[j];
            psum[ob + j] = a[j];
            pidx[ob + j] = ix[j];
        }
    }
}

// Kernel B: combine the 64 chunk-partials per column -> token + penalty term.
__global__ __launch_bounds__(256) void finalize_kernel(const float* __restrict__ pmax,
                                                       const float* __restrict__ psum,
                                                       const int* __restrict__ pidx,
                                                       int* __restrict__ toks,
                                                       float* __restrict__ pen) {
    const int col = blockIdx.x * 256 + threadIdx.x;   // 0..4095
    float m = -INFINITY;
    float sum = 0.f;
    int   idx = 0;
    for (int c = 0; c < NCHUNK; ++c) {
        const int off = c * NCOL + col;
        const float cm = pmax[off];
        const int   ci = pidx[off];
        sum += psum[off];
        if (cm > m || (cm == m && ci < idx)) { m = cm; idx = ci; }
    }
    // log_softmax at argmax: lprob = m - log(sum_exp)
    const float lprob = m - logf(sum);
    const float p = expf(lprob);
    float om = 1.0f - p;
    if (om < 1e-20f) om = 1e-20f;
    pen[col]  = -logf(om);
    toks[col] = idx;
}

__global__ void zero_kernel(float* out) { out[0] = 0.0f; }

// Kernel C: per-b repeat mask + masked penalty sum, atomicAdd (/B) into out.
__global__ __launch_bounds__(256) void mask_loss_kernel(const int* __restrict__ toks,
                                                        const float* __restrict__ pen,
                                                        float* __restrict__ out) {
    const int b   = blockIdx.x;
    const int tid = threadIdx.x;
    __shared__ int tk[SS];
    __shared__ int rep[SS];
    for (int i = tid; i < SS; i += 256) { tk[i] = toks[b * SS + i]; rep[i] = 0; }
    __syncthreads();

    for (int i = tid; i < PP; i += 256) {
        const int c0 = tk[i], c1 = tk[i + 1], c2 = tk[i + 2], c3 = tk[i + 3];
        int r = 0;
        for (int j = 0; j < i; ++j) {
            if (tk[j] == c0 && tk[j + 1] == c1 && tk[j + 2] == c2 && tk[j + 3] == c3) {
                r = 1; break;
            }
        }
        rep[i] = r;
    }
    __syncthreads();

    float local = 0.f;
    for (int s = tid; s < SS; s += 256) {
        int msk = 0;
#pragma unroll
        for (int k = 0; k < NGRAM; ++k) {
            const int i = s - k;
            if (i >= 0 && i < PP && rep[i]) msk = 1;
        }
        if (msk) local += pen[b * SS + s];
    }

    // wave(64) shuffle reduce, then cross-wave via LDS
    for (int off = 32; off > 0; off >>= 1) local += __shfl_down(local, off, 64);
    __shared__ float wsum[4];
    const int lane = tid & 63, wid = tid >> 6;
    if (lane == 0) wsum[wid] = local;
    __syncthreads();
    if (tid == 0) {
        float t = wsum[0] + wsum[1] + wsum[2] + wsum[3];
        atomicAdd(out, t * (1.0f / (float)BB));
    }
}

extern "C" void kernel_launch(void* const* d_in, const int* in_sizes, int n_in,
                              void* d_out, int out_size, void* d_ws, size_t ws_size,
                              hipStream_t stream) {
    const float* pred = (const float*)d_in[0];
    float* out = (float*)d_out;
    char* ws = (char*)d_ws;

    const size_t partN = (size_t)NCHUNK * NCOL;          // 262144
    float* pmax = (float*)ws;                             // 1 MB
    float* psum = (float*)(ws + partN * 4);               // 1 MB
    int*   pidx = (int*)  (ws + partN * 8);               // 1 MB
    int*   toks = (int*)  (ws + partN * 12);              // 16 KB
    float* pen  = (float*)(ws + partN * 12 + NCOL * 4);   // 16 KB

    colstats_kernel<<<BB * NCHUNK, 256, 0, stream>>>(pred, pmax, psum, pidx);
    finalize_kernel<<<NCOL / 256, 256, 0, stream>>>(pmax, psum, pidx, toks, pen);
    zero_kernel<<<1, 1, 0, stream>>>(out);
    mask_loss_kernel<<<BB, 256, 0, stream>>>(toks, pen, out);
}

// Round 2
// 755.920 us; speedup vs baseline: 1.0122x; 1.0122x over previous
//
#include <hip/hip_runtime.h>
#include <math.h>

#define BB 8
#define VV 32000
#define SS 512
#define NCHUNK 125
#define CHUNK 256               // NCHUNK * CHUNK == VV
#define NCOL (BB * SS)          // 4096
#define NGRAM 4
#define PP (SS - NGRAM)         // 508

// Kernel A: per-column (b,s) partial stats (max, argmax, sum-exp) over a V-chunk.
// 1000 blocks (~4/CU), 256 threads. vo = tid>>7 picks odd/even row stream,
// s = (tid&127)*4 gives 4 columns/thread via float4 loads (fully coalesced:
// a wave covers 1 KB contiguous).
__global__ __launch_bounds__(256) void colstats_kernel(const float* __restrict__ pred,
                                                       float* __restrict__ pmax,
                                                       float* __restrict__ psum,
                                                       int* __restrict__ pidx) {
    const int bid = blockIdx.x;
    const int b   = bid / NCHUNK;
    const int c   = bid - b * NCHUNK;
    const int tid = threadIdx.x;
    const int vo  = tid >> 7;
    const int s   = (tid & 127) << 2;
    const int v0  = c * CHUNK;

    float m0 = -INFINITY, m1 = -INFINITY, m2 = -INFINITY, m3 = -INFINITY;
    float a0 = 0.f, a1 = 0.f, a2 = 0.f, a3 = 0.f;
    int   i0 = 0, i1 = 0, i2 = 0, i3 = 0;

    const float L2E = 1.4426950408889634f;
    const float* ptr = pred + ((size_t)(b * VV + v0 + vo)) * SS + s;
    int v = v0 + vo;
#pragma unroll 8
    for (int k = 0; k < CHUNK / 2; ++k) {
        const float4 x = *(const float4*)ptr;
        ptr += 2 * SS;
        a0 += exp2f(x.x * L2E);
        a1 += exp2f(x.y * L2E);
        a2 += exp2f(x.z * L2E);
        a3 += exp2f(x.w * L2E);
        if (x.x > m0) { m0 = x.x; i0 = v; }
        if (x.y > m1) { m1 = x.y; i1 = v; }
        if (x.z > m2) { m2 = x.z; i2 = v; }
        if (x.w > m3) { m3 = x.w; i3 = v; }
        v += 2;
    }

    __shared__ float smax[256][4];
    __shared__ float ssum[256][4];
    __shared__ int   sidx[256][4];
    smax[tid][0] = m0; smax[tid][1] = m1; smax[tid][2] = m2; smax[tid][3] = m3;
    ssum[tid][0] = a0; ssum[tid][1] = a1; ssum[tid][2] = a2; ssum[tid][3] = a3;
    sidx[tid][0] = i0; sidx[tid][1] = i1; sidx[tid][2] = i2; sidx[tid][3] = i3;
    __syncthreads();

    if (tid < 128) {
        const int o = tid + 128;
        float m[4]  = {smax[tid][0], smax[tid][1], smax[tid][2], smax[tid][3]};
        float a[4]  = {ssum[tid][0], ssum[tid][1], ssum[tid][2], ssum[tid][3]};
        int   ix[4] = {sidx[tid][0], sidx[tid][1], sidx[tid][2], sidx[tid][3]};
#pragma unroll
        for (int j = 0; j < 4; ++j) {
            const float om = smax[o][j];
            const int   oi = sidx[o][j];
            a[j] += ssum[o][j];
            if (om > m[j] || (om == m[j] && oi < ix[j])) { m[j] = om; ix[j] = oi; }
        }
        const size_t ob = (size_t)c * NCOL + (size_t)b * SS + (size_t)s;
#pragma unroll
        for (int j = 0; j < 4; ++j) {
            pmax[ob + j] = m[j];
            psum[ob + j] = a[j];
            pidx[ob + j] = ix[j];
        }
    }
}

// Kernel B: combine the 125 chunk-partials per column -> token + penalty term.
// 64 blocks x 256 threads: 4 threads per column, ~32 chunks each, LDS combine.
__global__ __launch_bounds__(256) void finalize_kernel(const float* __restrict__ pmax,
                                                       const float* __restrict__ psum,
                                                       const int* __restrict__ pidx,
                                                       int* __restrict__ toks,
                                                       float* __restrict__ pen,
                                                       float* __restrict__ out) {
    const int tid  = threadIdx.x;
    const int col  = blockIdx.x * 64 + (tid >> 2);   // 0..4095
    const int part = tid & 3;

    if (blockIdx.x == 0 && tid == 0) out[0] = 0.0f;

    const int cbeg = part * 32;
    int cend = cbeg + 32; if (cend > NCHUNK) cend = NCHUNK;

    float m = -INFINITY, sum = 0.f;
    int   idx = 0x7fffffff;
    for (int c = cbeg; c < cend; ++c) {
        const int off = c * NCOL + col;
        const float cm = pmax[off];
        const int   ci = pidx[off];
        sum += psum[off];
        if (cm > m || (cm == m && ci < idx)) { m = cm; idx = ci; }
    }

    __shared__ float sm[256], ss[256];
    __shared__ int   si[256];
    sm[tid] = m; ss[tid] = sum; si[tid] = idx;
    __syncthreads();

    if (part == 0) {
#pragma unroll
        for (int j = 1; j < 4; ++j) {
            const float om = sm[tid + j];
            const int   oi = si[tid + j];
            sum += ss[tid + j];
            if (om > m || (om == m && oi < idx)) { m = om; idx = oi; }
        }
        // log_softmax at argmax: lprob = m - log(sum_exp); exp range is safe (|x|<~6)
        const float lprob = m - logf(sum);
        const float p = expf(lprob);
        float om1 = 1.0f - p;
        if (om1 < 1e-20f) om1 = 1e-20f;
        pen[col]  = -logf(om1);
        toks[col] = idx;
    }
}

// Kernel C: per-b repeat mask + masked penalty sum, atomicAdd (/B) into out.
__global__ __launch_bounds__(256) void mask_loss_kernel(const int* __restrict__ toks,
                                                        const float* __restrict__ pen,
                                                        float* __restrict__ out) {
    const int b   = blockIdx.x;
    const int tid = threadIdx.x;
    __shared__ int tk[SS];
    __shared__ int rep[SS];
    for (int i = tid; i < SS; i += 256) { tk[i] = toks[b * SS + i]; rep[i] = 0; }
    __syncthreads();

    for (int i = tid; i < PP; i += 256) {
        const int c0 = tk[i], c1 = tk[i + 1], c2 = tk[i + 2], c3 = tk[i + 3];
        int r = 0;
        for (int j = 0; j < i; ++j) {
            if (tk[j] == c0 && tk[j + 1] == c1 && tk[j + 2] == c2 && tk[j + 3] == c3) {
                r = 1; break;
            }
        }
        rep[i] = r;
    }
    __syncthreads();

    float local = 0.f;
    for (int s = tid; s < SS; s += 256) {
        int msk = 0;
#pragma unroll
        for (int k = 0; k < NGRAM; ++k) {
            const int i = s - k;
            if (i >= 0 && i < PP && rep[i]) msk = 1;
        }
        if (msk) local += pen[b * SS + s];
    }

    for (int off = 32; off > 0; off >>= 1) local += __shfl_down(local, off, 64);
    __shared__ float wsum[4];
    const int lane = tid & 63, wid = tid >> 6;
    if (lane == 0) wsum[wid] = local;
    __syncthreads();
    if (tid == 0) {
        float t = wsum[0] + wsum[1] + wsum[2] + wsum[3];
        atomicAdd(out, t * (1.0f / (float)BB));
    }
}

extern "C" void kernel_launch(void* const* d_in, const int* in_sizes, int n_in,
                              void* d_out, int out_size, void* d_ws, size_t ws_size,
                              hipStream_t stream) {
    const float* pred = (const float*)d_in[0];
    float* out = (float*)d_out;
    char* ws = (char*)d_ws;

    const size_t partN = (size_t)NCHUNK * NCOL;          // 512000
    float* pmax = (float*)ws;                             // 2.048 MB
    float* psum = (float*)(ws + partN * 4);
    int*   pidx = (int*)  (ws + partN * 8);
    int*   toks = (int*)  (ws + partN * 12);
    float* pen  = (float*)(ws + partN * 12 + NCOL * 4);

    colstats_kernel<<<BB * NCHUNK, 256, 0, stream>>>(pred, pmax, psum, pidx);
    finalize_kernel<<<NCOL / 64, 256, 0, stream>>>(pmax, psum, pidx, toks, pen, out);
    mask_loss_kernel<<<BB, 256, 0, stream>>>(toks, pen, out);
}